// Round 9
// baseline (61.926 us; speedup 1.0000x reference)
//
#include <hip/hip_runtime.h>
#include <math.h>

#define Bc 64
#define Nc 100
#define Fc 2048
#define Kc 16
#define NKc 8
#define BN (Bc*Nc)      // 6400
#define MO 1024
#define TWO_PI 6.283185307179586f

typedef __attribute__((ext_vector_type(8))) short bf16x8;
typedef __attribute__((ext_vector_type(4))) float f32x4;

__device__ __forceinline__ unsigned short f2bf(float x) {
    union { float f; unsigned u; } c; c.f = x;
    unsigned r = c.u + 0x7FFFu + ((c.u >> 16) & 1u);
    return (unsigned short)(r >> 16);
}
__device__ __forceinline__ float bf2f(unsigned short x) {
    return __uint_as_float((unsigned)x << 16);
}

// ---------------------------------------------------------------------------
// prep: blocks [0, nCvt) do fp32->bf16 for [v|W]; blocks [nCvt, ...) compute
// aw[bn][m][k] = adj * w / (sum_m w + 1e-14), 2 bn per 256-thread block.
// ---------------------------------------------------------------------------
__global__ __launch_bounds__(256) void prep(
    const float* __restrict__ v, const float* __restrict__ W,
    unsigned short* __restrict__ dst, int n8v, int nCvt,
    const float* __restrict__ coord, const float* __restrict__ adj,
    const int* __restrict__ top_ind,
    const float* __restrict__ mean_rho, const float* __restrict__ mean_theta,
    const float* __restrict__ prec_rho, const float* __restrict__ prec_theta,
    float* __restrict__ aw)
{
    const int bid = blockIdx.x;
    const int tid = threadIdx.x;
    if (bid < nCvt) {
        const int i = bid * 256 + tid;
        const float* src = (i < n8v) ? (v + (size_t)i * 8)
                                     : (W + (size_t)(i - n8v) * 8);
        const float4 x0 = ((const float4*)src)[0];
        const float4 x1 = ((const float4*)src)[1];
        bf16x8 o;
        o[0]=(short)f2bf(x0.x); o[1]=(short)f2bf(x0.y);
        o[2]=(short)f2bf(x0.z); o[3]=(short)f2bf(x0.w);
        o[4]=(short)f2bf(x1.x); o[5]=(short)f2bf(x1.y);
        o[6]=(short)f2bf(x1.z); o[7]=(short)f2bf(x1.w);
        *(bf16x8*)(dst + (size_t)i * 8) = o;
        return;
    }
    __shared__ int   idx[2][Kc];
    __shared__ float wv[2][Kc][NKc];
    __shared__ float sc[2][Kc];
    const int h  = tid >> 7;
    const int t7 = tid & 127;
    const int bn = (bid - nCvt) * 2 + h;
    if (t7 < Kc) idx[h][t7] = top_ind[bn * Kc + t7];
    __syncthreads();
    const int k = t7 >> 3, m = t7 & 7;
    const int j = idx[h][k];
    const float rho   = coord[((size_t)bn * Nc + j) * 2 + 0];
    const float theta = coord[((size_t)bn * Nc + j) * 2 + 1];
    const float dr = rho - mean_rho[m];
    const float pr = prec_rho[m];
    const float wr = expf(-0.5f * dr * dr / (1e-14f + pr * pr));
    const float fa = fabsf(theta - mean_theta[m]);
    const float sa = fabsf(TWO_PI - fa);
    const float da = fminf(fa, sa);
    const float pt = prec_theta[m];
    const float wt = expf(-0.5f * da * da / (1e-14f + pt * pt));
    float w = wr * wt;
    if (w != w) w = 0.0f;
    wv[h][k][m] = w;
    __syncthreads();
    if (t7 < Kc) {
        float s = 0.f;
        #pragma unroll
        for (int mm = 0; mm < NKc; ++mm) s += wv[h][t7][mm];
        sc[h][t7] = adj[bn * Kc + t7] / (s + 1e-14f);
    }
    __syncthreads();
    aw[(size_t)bn * 128 + m * 16 + k] = wv[h][k][m] * sc[h][k];
}

// ---------------------------------------------------------------------------
// gemm_fused (r8: counted-vmcnt pipeline, T4):
//   prologue stages tiles 0,1 (16 loads in flight); each iter waits only the
//   OLDEST stage (vmcnt(8)) -> barrier -> compute -> barrier -> stage(t+2).
//   Prefetch distance = one full iteration; 8 loads always in flight.
//   All stage issues are FULL-wave (A's tail issue covers rows 80..111,
//   rewriting rows 80..95 with identical bytes) so per-wave vmcnt counts
//   are exact and uniform.
// Geometry/swizzle/fusion identical to r7 (proven): block (b,jt) computes
// P_tile[112][128] and applies the in-LDS neighbor gather-reduce; XCD-local
// mapping keeps all 8 jt-blocks of a batch on one XCD.
//
// smem map (61,440 B):
//   K-loop:  Al[2][112][64] bf16 @ 0      (28,672 B)
//            Bl[2][128][64] bf16 @ 28,672 (32,768 B)
//   epilogue: P_lds[112][132] bf16 @ 0; idx @ 30,720; aw @ 37,120
// ---------------------------------------------------------------------------
#define GBM 112
#define GBN 128
#define GBK 64
#define NT (Fc/GBK)     // 32
#define A_OFF   0
#define A_BUF   14336
#define B_OFF   28672
#define B_BUF   16384
#define IDX_OFF 30720
#define AW_OFF  37120

#define WAIT_BAR(N) do { \
    asm volatile("s_waitcnt vmcnt(" #N ")" ::: "memory"); \
    __builtin_amdgcn_s_barrier(); \
    __builtin_amdgcn_sched_barrier(0); } while (0)

#define BAR() do { \
    __builtin_amdgcn_sched_barrier(0); \
    __builtin_amdgcn_s_barrier(); \
    __builtin_amdgcn_sched_barrier(0); } while (0)

template<int MI>
__device__ __forceinline__ void compute_tile(
    f32x4 (&acc)[4][4], const unsigned char* smem,
    int buf, int wm, int wn, int fr, int kg, int rsw)
{
    #pragma unroll
    for (int kk = 0; kk < 2; ++kk) {
        bf16x8 af[MI], bfr[4];
        #pragma unroll
        for (int mi = 0; mi < MI; ++mi)
            af[mi] = *(const bf16x8*)(smem + A_OFF + buf * A_BUF
                        + (wm * 64 + mi * 16 + fr) * 128
                        + ((kk * 32 + kg) ^ rsw) * 2);
        #pragma unroll
        for (int ni = 0; ni < 4; ++ni)
            bfr[ni] = *(const bf16x8*)(smem + B_OFF + buf * B_BUF
                        + (wn * 64 + ni * 16 + fr) * 128
                        + ((kk * 32 + kg) ^ rsw) * 2);
        #pragma unroll
        for (int mi = 0; mi < MI; ++mi)
            #pragma unroll
            for (int ni = 0; ni < 4; ++ni)
                acc[mi][ni] = __builtin_amdgcn_mfma_f32_16x16x32_bf16(
                    af[mi], bfr[ni], acc[mi][ni], 0, 0, 0);
    }
}

__global__ __launch_bounds__(256) void gemm_fused(
    const unsigned short* __restrict__ A,   // vb [6400][2048]
    const unsigned short* __restrict__ B,   // Wb [1024][2048]
    const float* __restrict__ aw,           // [6400][8][16]
    const int* __restrict__ top_ind,        // [6400][16]
    float* __restrict__ out)                // [6400][1024]
{
    __shared__ __align__(16) unsigned char smem[61440];

    const int tid = threadIdx.x;
    const int w  = tid >> 6, l = tid & 63;
    const int wm = w & 1,  wn = w >> 1;
    const int bid = blockIdx.x;
    const int xcd  = bid & 7;
    const int slot = bid >> 3;               // 0..63
    const int b  = xcd * 8 + (slot >> 3);    // batch 0..63 (XCD-local)
    const int jt = slot & 7;                 // kernel index / col tile
    const int i0 = b * Nc;
    const int j0 = jt * GBN;

    const int srow = tid >> 3;                       // 0..31
    const int scol = 8 * ((l & 7) ^ (l >> 3));       // pre-swizzled src col

    const int fr = l & 15;
    const int kg = (l >> 4) * 8;
    const int rsw = 8 * (fr & 7);

    f32x4 acc[4][4] = {};

    // 8 FULL issues per stage (uniform per-wave vmcnt): B rows 0..127 (4),
    // A rows 0..95 (3) + rows 80..111 (1, rows 80..95 double-written with
    // identical bytes; rows beyond BN-1 clamped per-lane).
    auto stage = [&](int buf, int t) {
        const size_t k0 = (size_t)t * GBK;
        #pragma unroll
        for (int q = 0; q < 4; ++q) {                // B: 128 rows
            const int row = q * 32 + srow;
            __builtin_amdgcn_global_load_lds(
                (const __attribute__((address_space(1))) void*)
                    (B + (size_t)(j0 + row) * Fc + k0 + scol),
                (__attribute__((address_space(3))) void*)
                    (smem + B_OFF + buf * B_BUF + q * 4096 + w * 1024),
                16, 0, 0);
        }
        #pragma unroll
        for (int q = 0; q < 3; ++q) {                // A rows 0..95
            const int row = i0 + q * 32 + srow;
            __builtin_amdgcn_global_load_lds(
                (const __attribute__((address_space(1))) void*)
                    (A + (size_t)row * Fc + k0 + scol),
                (__attribute__((address_space(3))) void*)
                    (smem + A_OFF + buf * A_BUF + q * 4096 + w * 1024),
                16, 0, 0);
        }
        {                                            // A rows 80..111 (full issue)
            int row = i0 + 80 + srow;
            if (row > BN - 1) row = BN - 1;
            __builtin_amdgcn_global_load_lds(
                (const __attribute__((address_space(1))) void*)
                    (A + (size_t)row * Fc + k0 + scol),
                (__attribute__((address_space(3))) void*)
                    (smem + A_OFF + buf * A_BUF + 10240 + w * 1024),
                16, 0, 0);
        }
    };

    #define COMPUTE(buf) do { \
        if (wm == 0) compute_tile<4>(acc, smem, (buf), wm, wn, fr, kg, rsw); \
        else         compute_tile<3>(acc, smem, (buf), wm, wn, fr, kg, rsw); \
    } while (0)

    stage(0, 0);
    stage(1, 1);            // 16 loads in flight
    #pragma unroll 2
    for (int t = 0; t + 2 < NT; ++t) {       // t = 0..NT-3
        WAIT_BAR(8);                         // oldest stage (tile t) landed
        COMPUTE(t & 1);
        BAR();                               // all waves done reading buf
        stage(t & 1, t + 2);                 // 8 issues -> back to 16 in flight
    }
    WAIT_BAR(8);                             // tile NT-2 landed
    COMPUTE(0);
    WAIT_BAR(0);                             // tile NT-1 landed
    COMPUTE(1);

    // ---- epilogue: P tile -> LDS (bf16, padded stride 132) ----
    __syncthreads();
    const int cn = l & 15;
    const int cr = (l >> 4) * 4;
    const int MIw = 4 - wm;
    #pragma unroll
    for (int mi = 0; mi < 4; ++mi) {
        if (mi < MIw) {
            #pragma unroll
            for (int ni = 0; ni < 4; ++ni) {
                #pragma unroll
                for (int r = 0; r < 4; ++r) {
                    const int row = wm * 64 + mi * 16 + cr + r;
                    const int col = wn * 64 + ni * 16 + cn;
                    *(unsigned short*)(smem + row * 264 + col * 2) =
                        f2bf(acc[mi][ni][r]);
                }
            }
        }
    }
    for (int i = tid; i < Nc * Kc; i += 256) {
        ((int*)(smem + IDX_OFF))[i] = top_ind[(size_t)b * Nc * Kc + i];
        ((float*)(smem + AW_OFF))[i] =
            aw[(size_t)(b * Nc + (i >> 4)) * 128 + jt * 16 + (i & 15)];
    }
    __syncthreads();

    // ---- combine: out[b,n,j0+c] = sum_k aw_k * P_lds[idx_k][c] ----
    const int cq = tid & 31;
    for (int n = tid >> 5; n < Nc; n += 8) {
        float4 o = make_float4(0.f, 0.f, 0.f, 0.f);
        #pragma unroll
        for (int k = 0; k < Kc; ++k) {
            const int   r = ((const int*)(smem + IDX_OFF))[n * Kc + k];
            const float a = ((const float*)(smem + AW_OFF))[n * Kc + k];
            const ushort4 u = *(const ushort4*)(smem + r * 264 + cq * 8);
            o.x += a * bf2f(u.x); o.y += a * bf2f(u.y);
            o.z += a * bf2f(u.z); o.w += a * bf2f(u.w);
        }
        *(float4*)&out[(size_t)(b * Nc + n) * MO + j0 + cq * 4] = o;
    }
}

// ---------------------------------------------------------------------------
// Fallback fp32 path (only if ws too small for bf16 path)
// ---------------------------------------------------------------------------
#define TM 64
#define TN 64
#define FBK 16

__device__ __forceinline__ void compute_a(
    int bn, int tid,
    const float* __restrict__ coord, const float* __restrict__ adj,
    const int* __restrict__ top_ind,
    const float* __restrict__ mean_rho, const float* __restrict__ mean_theta,
    const float* __restrict__ prec_rho, const float* __restrict__ prec_theta,
    int (&lds_idx)[Kc], float (&lds_a)[Kc][NKc], float (&lds_scale)[Kc])
{
    if (tid < Kc) lds_idx[tid] = top_ind[bn * Kc + tid];
    __syncthreads();
    if (tid < Kc * NKc) {
        const int k = tid >> 3, m = tid & 7;
        const int j = lds_idx[k];
        const float rho   = coord[((size_t)bn * Nc + j) * 2 + 0];
        const float theta = coord[((size_t)bn * Nc + j) * 2 + 1];
        const float dr = rho - mean_rho[m];
        const float pr = prec_rho[m];
        const float wr = expf(-0.5f * dr * dr / (1e-14f + pr * pr));
        const float fa = fabsf(theta - mean_theta[m]);
        const float sa = fabsf(TWO_PI - fa);
        const float da = fminf(fa, sa);
        const float pt = prec_theta[m];
        const float wt = expf(-0.5f * da * da / (1e-14f + pt * pt));
        float w = wr * wt;
        if (w != w) w = 0.0f;
        lds_a[k][m] = w;
    }
    __syncthreads();
    if (tid < Kc) {
        float s = 0.f;
        #pragma unroll
        for (int m = 0; m < NKc; ++m) s += lds_a[tid][m];
        lds_scale[tid] = adj[bn * Kc + tid] / (s + 1e-14f);
    }
    __syncthreads();
    if (tid < Kc * NKc) {
        const int k = tid >> 3, m = tid & 7;
        lds_a[k][m] *= lds_scale[k];
    }
    __syncthreads();
}

__global__ __launch_bounds__(256) void gemm_p(
    const float* __restrict__ A,
    const float* __restrict__ Bm,
    float* __restrict__ P)
{
    __shared__ float At[FBK][TM + 4];
    __shared__ float Bt[FBK][TN + 4];
    const int tid = threadIdx.x;
    const int tx = tid & 15;
    const int ty = tid >> 4;
    const int i0 = blockIdx.x * TM;
    const int j0 = blockIdx.y * TN;
    const int lk = tid & 15;
    const int lr = tid >> 4;

    float acc[4][4] = {};

    for (int k0 = 0; k0 < Fc; k0 += FBK) {
        #pragma unroll
        for (int rr = 0; rr < 4; ++rr) {
            At[lk][lr + rr * 16] = A[(size_t)(i0 + lr + rr * 16) * Fc + k0 + lk];
            Bt[lk][lr + rr * 16] = Bm[(size_t)(j0 + lr + rr * 16) * Fc + k0 + lk];
        }
        __syncthreads();
        #pragma unroll
        for (int kk = 0; kk < FBK; ++kk) {
            float a4[4], b4[4];
            #pragma unroll
            for (int p = 0; p < 4; ++p) a4[p] = At[kk][ty * 4 + p];
            #pragma unroll
            for (int p = 0; p < 4; ++p) b4[p] = Bt[kk][tx * 4 + p];
            #pragma unroll
            for (int pi = 0; pi < 4; ++pi)
                #pragma unroll
                for (int pj = 0; pj < 4; ++pj)
                    acc[pi][pj] += a4[pi] * b4[pj];
        }
        __syncthreads();
    }

    #pragma unroll
    for (int pi = 0; pi < 4; ++pi)
        #pragma unroll
        for (int pj = 0; pj < 4; ++pj)
            P[(size_t)(i0 + ty * 4 + pi) * MO + j0 + tx * 4 + pj] = acc[pi][pj];
}

__global__ __launch_bounds__(256) void combine_f32(
    const float* __restrict__ P,
    const float* __restrict__ coord, const float* __restrict__ adj,
    const int* __restrict__ top_ind,
    const float* __restrict__ mr, const float* __restrict__ mt,
    const float* __restrict__ pr, const float* __restrict__ pt,
    float* __restrict__ out)
{
    __shared__ int   lds_idx[Kc];
    __shared__ float lds_a[Kc][NKc];
    __shared__ float lds_scale[Kc];
    const int bn = blockIdx.x;
    const int tid = threadIdx.x;
    const int b = bn / Nc;

    compute_a(bn, tid, coord, adj, top_ind, mr, mt, pr, pt,
              lds_idx, lds_a, lds_scale);

    const int m = tid >> 5;
    float ak[Kc];
    size_t rowoff[Kc];
    #pragma unroll
    for (int k = 0; k < Kc; ++k) {
        ak[k] = lds_a[k][m];
        rowoff[k] = (size_t)(b * Nc + lds_idx[k]) * MO + tid * 4;
    }
    float4 acc = make_float4(0.f, 0.f, 0.f, 0.f);
    #pragma unroll
    for (int k = 0; k < Kc; ++k) {
        const float4 p = *(const float4*)&P[rowoff[k]];
        acc.x += ak[k] * p.x; acc.y += ak[k] * p.y;
        acc.z += ak[k] * p.z; acc.w += ak[k] * p.w;
    }
    *(float4*)&out[(size_t)bn * MO + tid * 4] = acc;
}

extern "C" void kernel_launch(void* const* d_in, const int* in_sizes, int n_in,
                              void* d_out, int out_size, void* d_ws, size_t ws_size,
                              hipStream_t stream) {
    const float* v        = (const float*)d_in[0];
    const float* coord    = (const float*)d_in[2];
    const float* adj      = (const float*)d_in[3];
    const int*   top_ind  = (const int*)d_in[4];
    const float* mr       = (const float*)d_in[5];
    const float* mt       = (const float*)d_in[6];
    const float* pr       = (const float*)d_in[7];
    const float* pt       = (const float*)d_in[8];
    const float* W        = (const float*)d_in[9];
    float* out = (float*)d_out;

    const size_t vbBytes = (size_t)BN * Fc * sizeof(unsigned short);   // 26,214,400
    const size_t WbBytes = (size_t)MO * Fc * sizeof(unsigned short);   //  4,194,304
    const size_t awBytes = (size_t)BN * 128 * sizeof(float);           //  3,276,800
    const size_t needBF  = vbBytes + WbBytes + awBytes;                // ~33.7 MB
    const size_t PBytes  = (size_t)BN * MO * sizeof(float);            // 26,214,400

    if (ws_size >= needBF) {
        char* ws = (char*)d_ws;
        unsigned short* vb = (unsigned short*)ws;                 // Wb follows vb
        unsigned short* Wb = vb + (size_t)BN * Fc;
        float* aw          = (float*)(ws + vbBytes + WbBytes);

        const int n8v   = BN * Fc / 8;                 // 1,638,400
        const int nCvt  = (n8v + MO * Fc / 8) / 256;   // 7424 (exact)
        const int nWgt  = BN / 2;                      // 3200
        prep<<<nCvt + nWgt, 256, 0, stream>>>(v, W, vb, n8v, nCvt,
                                              coord, adj, top_ind,
                                              mr, mt, pr, pt, aw);

        gemm_fused<<<512, 256, 0, stream>>>(vb, Wb, aw, top_ind, out);
    } else if (ws_size >= PBytes) {
        float* P = (float*)d_ws;
        gemm_p<<<dim3(BN / TM, MO / TN), 256, 0, stream>>>(v, W, P);
        combine_f32<<<BN, 256, 0, stream>>>(P, coord, adj, top_ind,
                                            mr, mt, pr, pt, out);
    }
}

// Round 10
// 61.821 us; speedup vs baseline: 1.0017x; 1.0017x over previous
//
#include <hip/hip_runtime.h>
#include <math.h>

#define Bc 64
#define Nc 100
#define Fc 2048
#define Kc 16
#define NKc 8
#define BN (Bc*Nc)      // 6400
#define MO 1024
#define TWO_PI 6.283185307179586f

typedef __attribute__((ext_vector_type(8))) short bf16x8;
typedef __attribute__((ext_vector_type(4))) float f32x4;

__device__ __forceinline__ unsigned short f2bf(float x) {
    union { float f; unsigned u; } c; c.f = x;
    unsigned r = c.u + 0x7FFFu + ((c.u >> 16) & 1u);
    return (unsigned short)(r >> 16);
}
__device__ __forceinline__ float bf2f(unsigned short x) {
    return __uint_as_float((unsigned)x << 16);
}

// ---------------------------------------------------------------------------
// prep: blocks [0, nCvt) do fp32->bf16 for [v|W]; blocks [nCvt, ...) compute
// aw[bn][m][k] = adj * w / (sum_m w + 1e-14), 2 bn per 256-thread block.
// ---------------------------------------------------------------------------
__global__ __launch_bounds__(256) void prep(
    const float* __restrict__ v, const float* __restrict__ W,
    unsigned short* __restrict__ dst, int n8v, int nCvt,
    const float* __restrict__ coord, const float* __restrict__ adj,
    const int* __restrict__ top_ind,
    const float* __restrict__ mean_rho, const float* __restrict__ mean_theta,
    const float* __restrict__ prec_rho, const float* __restrict__ prec_theta,
    float* __restrict__ aw)
{
    const int bid = blockIdx.x;
    const int tid = threadIdx.x;
    if (bid < nCvt) {
        const int i = bid * 256 + tid;
        const float* src = (i < n8v) ? (v + (size_t)i * 8)
                                     : (W + (size_t)(i - n8v) * 8);
        const float4 x0 = ((const float4*)src)[0];
        const float4 x1 = ((const float4*)src)[1];
        bf16x8 o;
        o[0]=(short)f2bf(x0.x); o[1]=(short)f2bf(x0.y);
        o[2]=(short)f2bf(x0.z); o[3]=(short)f2bf(x0.w);
        o[4]=(short)f2bf(x1.x); o[5]=(short)f2bf(x1.y);
        o[6]=(short)f2bf(x1.z); o[7]=(short)f2bf(x1.w);
        *(bf16x8*)(dst + (size_t)i * 8) = o;
        return;
    }
    __shared__ int   idx[2][Kc];
    __shared__ float wv[2][Kc][NKc];
    __shared__ float sc[2][Kc];
    const int h  = tid >> 7;
    const int t7 = tid & 127;
    const int bn = (bid - nCvt) * 2 + h;
    if (t7 < Kc) idx[h][t7] = top_ind[bn * Kc + t7];
    __syncthreads();
    const int k = t7 >> 3, m = t7 & 7;
    const int j = idx[h][k];
    const float rho   = coord[((size_t)bn * Nc + j) * 2 + 0];
    const float theta = coord[((size_t)bn * Nc + j) * 2 + 1];
    const float dr = rho - mean_rho[m];
    const float pr = prec_rho[m];
    const float wr = expf(-0.5f * dr * dr / (1e-14f + pr * pr));
    const float fa = fabsf(theta - mean_theta[m]);
    const float sa = fabsf(TWO_PI - fa);
    const float da = fminf(fa, sa);
    const float pt = prec_theta[m];
    const float wt = expf(-0.5f * da * da / (1e-14f + pt * pt));
    float w = wr * wt;
    if (w != w) w = 0.0f;
    wv[h][k][m] = w;
    __syncthreads();
    if (t7 < Kc) {
        float s = 0.f;
        #pragma unroll
        for (int mm = 0; mm < NKc; ++mm) s += wv[h][t7][mm];
        sc[h][t7] = adj[bn * Kc + t7] / (s + 1e-14f);
    }
    __syncthreads();
    aw[(size_t)bn * 128 + m * 16 + k] = wv[h][k][m] * sc[h][k];
}

// ---------------------------------------------------------------------------
// gemm_fused (r8: counted-vmcnt pipeline, T4):
//   prologue stages tiles 0,1 (16 loads in flight); each iter waits only the
//   OLDEST stage (vmcnt(8)) -> barrier -> compute -> barrier -> stage(t+2).
//   Prefetch distance = one full iteration; 8 loads always in flight.
//   All stage issues are FULL-wave (A's tail issue covers rows 80..111,
//   rewriting rows 80..95 with identical bytes) so per-wave vmcnt counts
//   are exact and uniform.
// Geometry/swizzle/fusion identical to r7 (proven): block (b,jt) computes
// P_tile[112][128] and applies the in-LDS neighbor gather-reduce; XCD-local
// mapping keeps all 8 jt-blocks of a batch on one XCD.
//
// smem map (61,440 B):
//   K-loop:  Al[2][112][64] bf16 @ 0      (28,672 B)
//            Bl[2][128][64] bf16 @ 28,672 (32,768 B)
//   epilogue: P_lds[112][132] bf16 @ 0; idx @ 30,720; aw @ 37,120
// ---------------------------------------------------------------------------
#define GBM 112
#define GBN 128
#define GBK 64
#define NT (Fc/GBK)     // 32
#define A_OFF   0
#define A_BUF   14336
#define B_OFF   28672
#define B_BUF   16384
#define IDX_OFF 30720
#define AW_OFF  37120

#define WAIT_BAR(N) do { \
    asm volatile("s_waitcnt vmcnt(" #N ")" ::: "memory"); \
    __builtin_amdgcn_s_barrier(); \
    __builtin_amdgcn_sched_barrier(0); } while (0)

#define BAR() do { \
    __builtin_amdgcn_sched_barrier(0); \
    __builtin_amdgcn_s_barrier(); \
    __builtin_amdgcn_sched_barrier(0); } while (0)

template<int MI>
__device__ __forceinline__ void compute_tile(
    f32x4 (&acc)[4][4], const unsigned char* smem,
    int buf, int wm, int wn, int fr, int kg, int rsw)
{
    #pragma unroll
    for (int kk = 0; kk < 2; ++kk) {
        bf16x8 af[MI], bfr[4];
        #pragma unroll
        for (int mi = 0; mi < MI; ++mi)
            af[mi] = *(const bf16x8*)(smem + A_OFF + buf * A_BUF
                        + (wm * 64 + mi * 16 + fr) * 128
                        + ((kk * 32 + kg) ^ rsw) * 2);
        #pragma unroll
        for (int ni = 0; ni < 4; ++ni)
            bfr[ni] = *(const bf16x8*)(smem + B_OFF + buf * B_BUF
                        + (wn * 64 + ni * 16 + fr) * 128
                        + ((kk * 32 + kg) ^ rsw) * 2);
        #pragma unroll
        for (int mi = 0; mi < MI; ++mi)
            #pragma unroll
            for (int ni = 0; ni < 4; ++ni)
                acc[mi][ni] = __builtin_amdgcn_mfma_f32_16x16x32_bf16(
                    af[mi], bfr[ni], acc[mi][ni], 0, 0, 0);
    }
}

__global__ __launch_bounds__(256) void gemm_fused(
    const unsigned short* __restrict__ A,   // vb [6400][2048]
    const unsigned short* __restrict__ B,   // Wb [1024][2048]
    const float* __restrict__ aw,           // [6400][8][16]
    const int* __restrict__ top_ind,        // [6400][16]
    float* __restrict__ out)                // [6400][1024]
{
    __shared__ __align__(16) unsigned char smem[61440];

    const int tid = threadIdx.x;
    const int w  = tid >> 6, l = tid & 63;
    const int wm = w & 1,  wn = w >> 1;
    const int bid = blockIdx.x;
    const int xcd  = bid & 7;
    const int slot = bid >> 3;               // 0..63
    const int b  = xcd * 8 + (slot >> 3);    // batch 0..63 (XCD-local)
    const int jt = slot & 7;                 // kernel index / col tile
    const int i0 = b * Nc;
    const int j0 = jt * GBN;

    const int srow = tid >> 3;                       // 0..31
    const int scol = 8 * ((l & 7) ^ (l >> 3));       // pre-swizzled src col

    const int fr = l & 15;
    const int kg = (l >> 4) * 8;
    const int rsw = 8 * (fr & 7);

    f32x4 acc[4][4] = {};

    // 8 FULL issues per stage (uniform per-wave vmcnt): B rows 0..127 (4),
    // A rows 0..95 (3) + rows 80..111 (1, rows 80..95 double-written with
    // identical bytes; rows beyond BN-1 clamped per-lane).
    auto stage = [&](int buf, int t) {
        const size_t k0 = (size_t)t * GBK;
        #pragma unroll
        for (int q = 0; q < 4; ++q) {                // B: 128 rows
            const int row = q * 32 + srow;
            __builtin_amdgcn_global_load_lds(
                (const __attribute__((address_space(1))) void*)
                    (B + (size_t)(j0 + row) * Fc + k0 + scol),
                (__attribute__((address_space(3))) void*)
                    (smem + B_OFF + buf * B_BUF + q * 4096 + w * 1024),
                16, 0, 0);
        }
        #pragma unroll
        for (int q = 0; q < 3; ++q) {                // A rows 0..95
            const int row = i0 + q * 32 + srow;
            __builtin_amdgcn_global_load_lds(
                (const __attribute__((address_space(1))) void*)
                    (A + (size_t)row * Fc + k0 + scol),
                (__attribute__((address_space(3))) void*)
                    (smem + A_OFF + buf * A_BUF + q * 4096 + w * 1024),
                16, 0, 0);
        }
        {                                            // A rows 80..111 (full issue)
            int row = i0 + 80 + srow;
            if (row > BN - 1) row = BN - 1;
            __builtin_amdgcn_global_load_lds(
                (const __attribute__((address_space(1))) void*)
                    (A + (size_t)row * Fc + k0 + scol),
                (__attribute__((address_space(3))) void*)
                    (smem + A_OFF + buf * A_BUF + 10240 + w * 1024),
                16, 0, 0);
        }
    };

    #define COMPUTE(buf) do { \
        if (wm == 0) compute_tile<4>(acc, smem, (buf), wm, wn, fr, kg, rsw); \
        else         compute_tile<3>(acc, smem, (buf), wm, wn, fr, kg, rsw); \
    } while (0)

    stage(0, 0);
    stage(1, 1);            // 16 loads in flight
    #pragma unroll 2
    for (int t = 0; t + 2 < NT; ++t) {       // t = 0..NT-3
        WAIT_BAR(8);                         // oldest stage (tile t) landed
        COMPUTE(t & 1);
        BAR();                               // all waves done reading buf
        stage(t & 1, t + 2);                 // 8 issues -> back to 16 in flight
    }
    WAIT_BAR(8);                             // tile NT-2 landed
    COMPUTE(0);
    WAIT_BAR(0);                             // tile NT-1 landed
    COMPUTE(1);

    // ---- epilogue: P tile -> LDS (bf16, padded stride 132) ----
    __syncthreads();
    const int cn = l & 15;
    const int cr = (l >> 4) * 4;
    const int MIw = 4 - wm;
    #pragma unroll
    for (int mi = 0; mi < 4; ++mi) {
        if (mi < MIw) {
            #pragma unroll
            for (int ni = 0; ni < 4; ++ni) {
                #pragma unroll
                for (int r = 0; r < 4; ++r) {
                    const int row = wm * 64 + mi * 16 + cr + r;
                    const int col = wn * 64 + ni * 16 + cn;
                    *(unsigned short*)(smem + row * 264 + col * 2) =
                        f2bf(acc[mi][ni][r]);
                }
            }
        }
    }
    for (int i = tid; i < Nc * Kc; i += 256) {
        ((int*)(smem + IDX_OFF))[i] = top_ind[(size_t)b * Nc * Kc + i];
        ((float*)(smem + AW_OFF))[i] =
            aw[(size_t)(b * Nc + (i >> 4)) * 128 + jt * 16 + (i & 15)];
    }
    __syncthreads();

    // ---- combine: out[b,n,j0+c] = sum_k aw_k * P_lds[idx_k][c] ----
    const int cq = tid & 31;
    for (int n = tid >> 5; n < Nc; n += 8) {
        float4 o = make_float4(0.f, 0.f, 0.f, 0.f);
        #pragma unroll
        for (int k = 0; k < Kc; ++k) {
            const int   r = ((const int*)(smem + IDX_OFF))[n * Kc + k];
            const float a = ((const float*)(smem + AW_OFF))[n * Kc + k];
            const ushort4 u = *(const ushort4*)(smem + r * 264 + cq * 8);
            o.x += a * bf2f(u.x); o.y += a * bf2f(u.y);
            o.z += a * bf2f(u.z); o.w += a * bf2f(u.w);
        }
        *(float4*)&out[(size_t)(b * Nc + n) * MO + j0 + cq * 4] = o;
    }
}

// ---------------------------------------------------------------------------
// Fallback fp32 path (only if ws too small for bf16 path)
// ---------------------------------------------------------------------------
#define TM 64
#define TN 64
#define FBK 16

__device__ __forceinline__ void compute_a(
    int bn, int tid,
    const float* __restrict__ coord, const float* __restrict__ adj,
    const int* __restrict__ top_ind,
    const float* __restrict__ mean_rho, const float* __restrict__ mean_theta,
    const float* __restrict__ prec_rho, const float* __restrict__ prec_theta,
    int (&lds_idx)[Kc], float (&lds_a)[Kc][NKc], float (&lds_scale)[Kc])
{
    if (tid < Kc) lds_idx[tid] = top_ind[bn * Kc + tid];
    __syncthreads();
    if (tid < Kc * NKc) {
        const int k = tid >> 3, m = tid & 7;
        const int j = lds_idx[k];
        const float rho   = coord[((size_t)bn * Nc + j) * 2 + 0];
        const float theta = coord[((size_t)bn * Nc + j) * 2 + 1];
        const float dr = rho - mean_rho[m];
        const float pr = prec_rho[m];
        const float wr = expf(-0.5f * dr * dr / (1e-14f + pr * pr));
        const float fa = fabsf(theta - mean_theta[m]);
        const float sa = fabsf(TWO_PI - fa);
        const float da = fminf(fa, sa);
        const float pt = prec_theta[m];
        const float wt = expf(-0.5f * da * da / (1e-14f + pt * pt));
        float w = wr * wt;
        if (w != w) w = 0.0f;
        lds_a[k][m] = w;
    }
    __syncthreads();
    if (tid < Kc) {
        float s = 0.f;
        #pragma unroll
        for (int m = 0; m < NKc; ++m) s += lds_a[tid][m];
        lds_scale[tid] = adj[bn * Kc + tid] / (s + 1e-14f);
    }
    __syncthreads();
    if (tid < Kc * NKc) {
        const int k = tid >> 3, m = tid & 7;
        lds_a[k][m] *= lds_scale[k];
    }
    __syncthreads();
}

__global__ __launch_bounds__(256) void gemm_p(
    const float* __restrict__ A,
    const float* __restrict__ Bm,
    float* __restrict__ P)
{
    __shared__ float At[FBK][TM + 4];
    __shared__ float Bt[FBK][TN + 4];
    const int tid = threadIdx.x;
    const int tx = tid & 15;
    const int ty = tid >> 4;
    const int i0 = blockIdx.x * TM;
    const int j0 = blockIdx.y * TN;
    const int lk = tid & 15;
    const int lr = tid >> 4;

    float acc[4][4] = {};

    for (int k0 = 0; k0 < Fc; k0 += FBK) {
        #pragma unroll
        for (int rr = 0; rr < 4; ++rr) {
            At[lk][lr + rr * 16] = A[(size_t)(i0 + lr + rr * 16) * Fc + k0 + lk];
            Bt[lk][lr + rr * 16] = Bm[(size_t)(j0 + lr + rr * 16) * Fc + k0 + lk];
        }
        __syncthreads();
        #pragma unroll
        for (int kk = 0; kk < FBK; ++kk) {
            float a4[4], b4[4];
            #pragma unroll
            for (int p = 0; p < 4; ++p) a4[p] = At[kk][ty * 4 + p];
            #pragma unroll
            for (int p = 0; p < 4; ++p) b4[p] = Bt[kk][tx * 4 + p];
            #pragma unroll
            for (int pi = 0; pi < 4; ++pi)
                #pragma unroll
                for (int pj = 0; pj < 4; ++pj)
                    acc[pi][pj] += a4[pi] * b4[pj];
        }
        __syncthreads();
    }

    #pragma unroll
    for (int pi = 0; pi < 4; ++pi)
        #pragma unroll
        for (int pj = 0; pj < 4; ++pj)
            P[(size_t)(i0 + ty * 4 + pi) * MO + j0 + tx * 4 + pj] = acc[pi][pj];
}

__global__ __launch_bounds__(256) void combine_f32(
    const float* __restrict__ P,
    const float* __restrict__ coord, const float* __restrict__ adj,
    const int* __restrict__ top_ind,
    const float* __restrict__ mr, const float* __restrict__ mt,
    const float* __restrict__ pr, const float* __restrict__ pt,
    float* __restrict__ out)
{
    __shared__ int   lds_idx[Kc];
    __shared__ float lds_a[Kc][NKc];
    __shared__ float lds_scale[Kc];
    const int bn = blockIdx.x;
    const int tid = threadIdx.x;
    const int b = bn / Nc;

    compute_a(bn, tid, coord, adj, top_ind, mr, mt, pr, pt,
              lds_idx, lds_a, lds_scale);

    const int m = tid >> 5;
    float ak[Kc];
    size_t rowoff[Kc];
    #pragma unroll
    for (int k = 0; k < Kc; ++k) {
        ak[k] = lds_a[k][m];
        rowoff[k] = (size_t)(b * Nc + lds_idx[k]) * MO + tid * 4;
    }
    float4 acc = make_float4(0.f, 0.f, 0.f, 0.f);
    #pragma unroll
    for (int k = 0; k < Kc; ++k) {
        const float4 p = *(const float4*)&P[rowoff[k]];
        acc.x += ak[k] * p.x; acc.y += ak[k] * p.y;
        acc.z += ak[k] * p.z; acc.w += ak[k] * p.w;
    }
    *(float4*)&out[(size_t)bn * MO + tid * 4] = acc;
}

extern "C" void kernel_launch(void* const* d_in, const int* in_sizes, int n_in,
                              void* d_out, int out_size, void* d_ws, size_t ws_size,
                              hipStream_t stream) {
    const float* v        = (const float*)d_in[0];
    const float* coord    = (const float*)d_in[2];
    const float* adj      = (const float*)d_in[3];
    const int*   top_ind  = (const int*)d_in[4];
    const float* mr       = (const float*)d_in[5];
    const float* mt       = (const float*)d_in[6];
    const float* pr       = (const float*)d_in[7];
    const float* pt       = (const float*)d_in[8];
    const float* W        = (const float*)d_in[9];
    float* out = (float*)d_out;

    const size_t vbBytes = (size_t)BN * Fc * sizeof(unsigned short);   // 26,214,400
    const size_t WbBytes = (size_t)MO * Fc * sizeof(unsigned short);   //  4,194,304
    const size_t awBytes = (size_t)BN * 128 * sizeof(float);           //  3,276,800
    const size_t needBF  = vbBytes + WbBytes + awBytes;                // ~33.7 MB
    const size_t PBytes  = (size_t)BN * MO * sizeof(float);            // 26,214,400

    if (ws_size >= needBF) {
        char* ws = (char*)d_ws;
        unsigned short* vb = (unsigned short*)ws;                 // Wb follows vb
        unsigned short* Wb = vb + (size_t)BN * Fc;
        float* aw          = (float*)(ws + vbBytes + WbBytes);

        const int n8v   = BN * Fc / 8;                 // 1,638,400
        const int nCvt  = (n8v + MO * Fc / 8) / 256;   // 7424 (exact)
        const int nWgt  = BN / 2;                      // 3200
        prep<<<nCvt + nWgt, 256, 0, stream>>>(v, W, vb, n8v, nCvt,
                                              coord, adj, top_ind,
                                              mr, mt, pr, pt, aw);

        gemm_fused<<<512, 256, 0, stream>>>(vb, Wb, aw, top_ind, out);
    } else if (ws_size >= PBytes) {
        float* P = (float*)d_ws;
        gemm_p<<<dim3(BN / TM, MO / TN), 256, 0, stream>>>(v, W, P);
        combine_f32<<<BN, 256, 0, stream>>>(P, coord, adj, top_ind,
                                            mr, mt, pr, pt, out);
    }
}

// Round 11
// 58.763 us; speedup vs baseline: 1.0538x; 1.0520x over previous
//
#include <hip/hip_runtime.h>
#include <math.h>

#define Bc 64
#define Nc 100
#define Fc 2048
#define Kc 16
#define NKc 8
#define BN (Bc*Nc)      // 6400
#define MO 1024
#define TWO_PI 6.283185307179586f

typedef __attribute__((ext_vector_type(8))) short bf16x8;
typedef __attribute__((ext_vector_type(4))) float f32x4;

__device__ __forceinline__ unsigned short f2bf(float x) {
    union { float f; unsigned u; } c; c.f = x;
    unsigned r = c.u + 0x7FFFu + ((c.u >> 16) & 1u);
    return (unsigned short)(r >> 16);
}
__device__ __forceinline__ float bf2f(unsigned short x) {
    return __uint_as_float((unsigned)x << 16);
}

// ---------------------------------------------------------------------------
// prep: blocks [0, nCvt) do fp32->bf16 for [v|W]; blocks [nCvt, ...) compute
// aw[bn][m][k] = adj * w / (sum_m w + 1e-14), 2 bn per 256-thread block.
// ---------------------------------------------------------------------------
__global__ __launch_bounds__(256) void prep(
    const float* __restrict__ v, const float* __restrict__ W,
    unsigned short* __restrict__ dst, int n8v, int nCvt,
    const float* __restrict__ coord, const float* __restrict__ adj,
    const int* __restrict__ top_ind,
    const float* __restrict__ mean_rho, const float* __restrict__ mean_theta,
    const float* __restrict__ prec_rho, const float* __restrict__ prec_theta,
    float* __restrict__ aw)
{
    const int bid = blockIdx.x;
    const int tid = threadIdx.x;
    if (bid < nCvt) {
        const int i = bid * 256 + tid;
        const float* src = (i < n8v) ? (v + (size_t)i * 8)
                                     : (W + (size_t)(i - n8v) * 8);
        const float4 x0 = ((const float4*)src)[0];
        const float4 x1 = ((const float4*)src)[1];
        bf16x8 o;
        o[0]=(short)f2bf(x0.x); o[1]=(short)f2bf(x0.y);
        o[2]=(short)f2bf(x0.z); o[3]=(short)f2bf(x0.w);
        o[4]=(short)f2bf(x1.x); o[5]=(short)f2bf(x1.y);
        o[6]=(short)f2bf(x1.z); o[7]=(short)f2bf(x1.w);
        *(bf16x8*)(dst + (size_t)i * 8) = o;
        return;
    }
    __shared__ int   idx[2][Kc];
    __shared__ float wv[2][Kc][NKc];
    __shared__ float sc[2][Kc];
    const int h  = tid >> 7;
    const int t7 = tid & 127;
    const int bn = (bid - nCvt) * 2 + h;
    if (t7 < Kc) idx[h][t7] = top_ind[bn * Kc + t7];
    __syncthreads();
    const int k = t7 >> 3, m = t7 & 7;
    const int j = idx[h][k];
    const float rho   = coord[((size_t)bn * Nc + j) * 2 + 0];
    const float theta = coord[((size_t)bn * Nc + j) * 2 + 1];
    const float dr = rho - mean_rho[m];
    const float pr = prec_rho[m];
    const float wr = expf(-0.5f * dr * dr / (1e-14f + pr * pr));
    const float fa = fabsf(theta - mean_theta[m]);
    const float sa = fabsf(TWO_PI - fa);
    const float da = fminf(fa, sa);
    const float pt = prec_theta[m];
    const float wt = expf(-0.5f * da * da / (1e-14f + pt * pt));
    float w = wr * wt;
    if (w != w) w = 0.0f;
    wv[h][k][m] = w;
    __syncthreads();
    if (t7 < Kc) {
        float s = 0.f;
        #pragma unroll
        for (int mm = 0; mm < NKc; ++mm) s += wv[h][t7][mm];
        sc[h][t7] = adj[bn * Kc + t7] / (s + 1e-14f);
    }
    __syncthreads();
    aw[(size_t)bn * 128 + m * 16 + k] = wv[h][k][m] * sc[h][k];
}

// ---------------------------------------------------------------------------
// gemm_fused (r11: 512-thread / 8-wave blocks for 4 waves/SIMD TLP):
//   grid 512 (exact 2 blocks/CU -> 16 waves/CU), tile 112x128, BK=64,
//   wave grid 2(M) x 4(N), wave tile (64|48)x32, acc = 8 frags (32 VGPR).
//   r7-proven SYNC loop (stage(next) -> compute(cur) -> vmcnt0+barrier),
//   XOR swizzle both-sides, XCD-local (b,jt) mapping, fused in-LDS gather.
//   Staging = 4 full-wave global_load_lds issues/step (A rows 48..63 are
//   double-written with identical bytes; tail rows clamped per-lane).
//
// smem map (61,440 B):
//   K-loop:  Al[2][112][64] bf16 @ 0      (28,672 B)
//            Bl[2][128][64] bf16 @ 28,672 (32,768 B)
//   epilogue: P_lds[112][132] bf16 @ 0; idx @ 30,720; aw @ 37,120
// ---------------------------------------------------------------------------
#define GBM 112
#define GBN 128
#define GBK 64
#define NT (Fc/GBK)     // 32
#define A_OFF   0
#define A_BUF   14336
#define B_OFF   28672
#define B_BUF   16384
#define IDX_OFF 30720
#define AW_OFF  37120

#define SYNC() do { asm volatile("s_waitcnt vmcnt(0)" ::: "memory"); \
                    __builtin_amdgcn_s_barrier(); \
                    __builtin_amdgcn_sched_barrier(0); } while (0)

template<int MI>
__device__ __forceinline__ void compute_tile(
    f32x4 (&acc)[4][2], const unsigned char* smem,
    int buf, int wm, int wn, int fr, int kg, int rsw)
{
    #pragma unroll
    for (int kk = 0; kk < 2; ++kk) {
        bf16x8 af[MI], bfr[2];
        #pragma unroll
        for (int mi = 0; mi < MI; ++mi)
            af[mi] = *(const bf16x8*)(smem + A_OFF + buf * A_BUF
                        + (wm * 64 + mi * 16 + fr) * 128
                        + ((kk * 32 + kg) ^ rsw) * 2);
        #pragma unroll
        for (int ni = 0; ni < 2; ++ni)
            bfr[ni] = *(const bf16x8*)(smem + B_OFF + buf * B_BUF
                        + (wn * 32 + ni * 16 + fr) * 128
                        + ((kk * 32 + kg) ^ rsw) * 2);
        #pragma unroll
        for (int mi = 0; mi < MI; ++mi)
            #pragma unroll
            for (int ni = 0; ni < 2; ++ni)
                acc[mi][ni] = __builtin_amdgcn_mfma_f32_16x16x32_bf16(
                    af[mi], bfr[ni], acc[mi][ni], 0, 0, 0);
    }
}

__global__ __launch_bounds__(512, 4) void gemm_fused(
    const unsigned short* __restrict__ A,   // vb [6400][2048]
    const unsigned short* __restrict__ B,   // Wb [1024][2048]
    const float* __restrict__ aw,           // [6400][8][16]
    const int* __restrict__ top_ind,        // [6400][16]
    float* __restrict__ out)                // [6400][1024]
{
    __shared__ __align__(16) unsigned char smem[61440];

    const int tid = threadIdx.x;
    const int w  = tid >> 6, l = tid & 63;
    const int wm = w >> 2;                   // 0..1 (M half)
    const int wn = w & 3;                    // 0..3 (N quarter)
    const int bid = blockIdx.x;
    const int xcd  = bid & 7;
    const int slot = bid >> 3;               // 0..63
    const int b  = xcd * 8 + (slot >> 3);    // batch 0..63 (XCD-local)
    const int jt = slot & 7;                 // kernel index / col tile
    const int i0 = b * Nc;
    const int j0 = jt * GBN;

    const int srow = tid >> 3;                       // 0..63
    const int scol = 8 * ((l & 7) ^ (l >> 3));       // pre-swizzled src col
    // (row & 7 == l>>3 for every issue: all issue row-bases are 0 mod 8)

    const int fr = l & 15;
    const int kg = (l >> 4) * 8;
    const int rsw = 8 * (fr & 7);

    f32x4 acc[4][2] = {};

    // 4 full-wave issues per stage: B rows 0..63, 64..127; A rows 0..63,
    // A rows 48..111 (48..63 double-written with identical bytes; rows
    // beyond BN-1 clamped per-lane — clamped rows are never gathered).
    auto stage = [&](int buf, int t) {
        const size_t k0 = (size_t)t * GBK;
        #pragma unroll
        for (int q = 0; q < 2; ++q) {                // B: 128 rows
            const int row = q * 64 + srow;
            __builtin_amdgcn_global_load_lds(
                (const __attribute__((address_space(1))) void*)
                    (B + (size_t)(j0 + row) * Fc + k0 + scol),
                (__attribute__((address_space(3))) void*)
                    (smem + B_OFF + buf * B_BUF + q * 8192 + w * 1024),
                16, 0, 0);
        }
        {                                            // A rows 0..63
            const int row = i0 + srow;
            __builtin_amdgcn_global_load_lds(
                (const __attribute__((address_space(1))) void*)
                    (A + (size_t)row * Fc + k0 + scol),
                (__attribute__((address_space(3))) void*)
                    (smem + A_OFF + buf * A_BUF + w * 1024),
                16, 0, 0);
        }
        {                                            // A rows 48..111
            int row = i0 + 48 + srow;
            if (row > BN - 1) row = BN - 1;
            __builtin_amdgcn_global_load_lds(
                (const __attribute__((address_space(1))) void*)
                    (A + (size_t)row * Fc + k0 + scol),
                (__attribute__((address_space(3))) void*)
                    (smem + A_OFF + buf * A_BUF + 6144 + w * 1024),
                16, 0, 0);
        }
    };

    #define COMPUTE(buf) do { \
        if (wm == 0) compute_tile<4>(acc, smem, (buf), wm, wn, fr, kg, rsw); \
        else         compute_tile<3>(acc, smem, (buf), wm, wn, fr, kg, rsw); \
    } while (0)

    stage(0, 0);
    SYNC();
    int t = 0;
    for (; t + 2 < NT; t += 2) {
        stage(1, t + 1);  COMPUTE(0);  SYNC();
        stage(0, t + 2);  COMPUTE(1);  SYNC();
    }
    stage(1, NT - 1);  COMPUTE(0);  SYNC();
    COMPUTE(1);

    // ---- epilogue: P tile -> LDS (bf16, padded stride 132) ----
    __syncthreads();
    const int cn = l & 15;
    const int cr = (l >> 4) * 4;
    const int MIw = 4 - wm;   // wave row 0: rows 0..63 (4 frags); 1: 64..111 (3)
    #pragma unroll
    for (int mi = 0; mi < 4; ++mi) {
        if (mi < MIw) {
            #pragma unroll
            for (int ni = 0; ni < 2; ++ni) {
                #pragma unroll
                for (int r = 0; r < 4; ++r) {
                    const int row = wm * 64 + mi * 16 + cr + r;
                    const int col = wn * 32 + ni * 16 + cn;
                    *(unsigned short*)(smem + row * 264 + col * 2) =
                        f2bf(acc[mi][ni][r]);
                }
            }
        }
    }
    for (int i = tid; i < Nc * Kc; i += 512) {
        ((int*)(smem + IDX_OFF))[i] = top_ind[(size_t)b * Nc * Kc + i];
        ((float*)(smem + AW_OFF))[i] =
            aw[(size_t)(b * Nc + (i >> 4)) * 128 + jt * 16 + (i & 15)];
    }
    __syncthreads();

    // ---- combine: out[b,n,j0+c] = sum_k aw_k * P_lds[idx_k][c] ----
    const int cq = tid & 31;
    for (int n = tid >> 5; n < Nc; n += 16) {
        float4 o = make_float4(0.f, 0.f, 0.f, 0.f);
        #pragma unroll
        for (int k = 0; k < Kc; ++k) {
            const int   r = ((const int*)(smem + IDX_OFF))[n * Kc + k];
            const float a = ((const float*)(smem + AW_OFF))[n * Kc + k];
            const ushort4 u = *(const ushort4*)(smem + r * 264 + cq * 8);
            o.x += a * bf2f(u.x); o.y += a * bf2f(u.y);
            o.z += a * bf2f(u.z); o.w += a * bf2f(u.w);
        }
        *(float4*)&out[(size_t)(b * Nc + n) * MO + j0 + cq * 4] = o;
    }
}

// ---------------------------------------------------------------------------
// Fallback fp32 path (only if ws too small for bf16 path)
// ---------------------------------------------------------------------------
#define TM 64
#define TN 64
#define FBK 16

__device__ __forceinline__ void compute_a(
    int bn, int tid,
    const float* __restrict__ coord, const float* __restrict__ adj,
    const int* __restrict__ top_ind,
    const float* __restrict__ mean_rho, const float* __restrict__ mean_theta,
    const float* __restrict__ prec_rho, const float* __restrict__ prec_theta,
    int (&lds_idx)[Kc], float (&lds_a)[Kc][NKc], float (&lds_scale)[Kc])
{
    if (tid < Kc) lds_idx[tid] = top_ind[bn * Kc + tid];
    __syncthreads();
    if (tid < Kc * NKc) {
        const int k = tid >> 3, m = tid & 7;
        const int j = lds_idx[k];
        const float rho   = coord[((size_t)bn * Nc + j) * 2 + 0];
        const float theta = coord[((size_t)bn * Nc + j) * 2 + 1];
        const float dr = rho - mean_rho[m];
        const float pr = prec_rho[m];
        const float wr = expf(-0.5f * dr * dr / (1e-14f + pr * pr));
        const float fa = fabsf(theta - mean_theta[m]);
        const float sa = fabsf(TWO_PI - fa);
        const float da = fminf(fa, sa);
        const float pt = prec_theta[m];
        const float wt = expf(-0.5f * da * da / (1e-14f + pt * pt));
        float w = wr * wt;
        if (w != w) w = 0.0f;
        lds_a[k][m] = w;
    }
    __syncthreads();
    if (tid < Kc) {
        float s = 0.f;
        #pragma unroll
        for (int m = 0; m < NKc; ++m) s += lds_a[tid][m];
        lds_scale[tid] = adj[bn * Kc + tid] / (s + 1e-14f);
    }
    __syncthreads();
    if (tid < Kc * NKc) {
        const int k = tid >> 3, m = tid & 7;
        lds_a[k][m] *= lds_scale[k];
    }
    __syncthreads();
}

__global__ __launch_bounds__(256) void gemm_p(
    const float* __restrict__ A,
    const float* __restrict__ Bm,
    float* __restrict__ P)
{
    __shared__ float At[FBK][TM + 4];
    __shared__ float Bt[FBK][TN + 4];
    const int tid = threadIdx.x;
    const int tx = tid & 15;
    const int ty = tid >> 4;
    const int i0 = blockIdx.x * TM;
    const int j0 = blockIdx.y * TN;
    const int lk = tid & 15;
    const int lr = tid >> 4;

    float acc[4][4] = {};

    for (int k0 = 0; k0 < Fc; k0 += FBK) {
        #pragma unroll
        for (int rr = 0; rr < 4; ++rr) {
            At[lk][lr + rr * 16] = A[(size_t)(i0 + lr + rr * 16) * Fc + k0 + lk];
            Bt[lk][lr + rr * 16] = Bm[(size_t)(j0 + lr + rr * 16) * Fc + k0 + lk];
        }
        __syncthreads();
        #pragma unroll
        for (int kk = 0; kk < FBK; ++kk) {
            float a4[4], b4[4];
            #pragma unroll
            for (int p = 0; p < 4; ++p) a4[p] = At[kk][ty * 4 + p];
            #pragma unroll
            for (int p = 0; p < 4; ++p) b4[p] = Bt[kk][tx * 4 + p];
            #pragma unroll
            for (int pi = 0; pi < 4; ++pi)
                #pragma unroll
                for (int pj = 0; pj < 4; ++pj)
                    acc[pi][pj] += a4[pi] * b4[pj];
        }
        __syncthreads();
    }

    #pragma unroll
    for (int pi = 0; pi < 4; ++pi)
        #pragma unroll
        for (int pj = 0; pj < 4; ++pj)
            P[(size_t)(i0 + ty * 4 + pi) * MO + j0 + tx * 4 + pj] = acc[pi][pj];
}

__global__ __launch_bounds__(256) void combine_f32(
    const float* __restrict__ P,
    const float* __restrict__ coord, const float* __restrict__ adj,
    const int* __restrict__ top_ind,
    const float* __restrict__ mr, const float* __restrict__ mt,
    const float* __restrict__ pr, const float* __restrict__ pt,
    float* __restrict__ out)
{
    __shared__ int   lds_idx[Kc];
    __shared__ float lds_a[Kc][NKc];
    __shared__ float lds_scale[Kc];
    const int bn = blockIdx.x;
    const int tid = threadIdx.x;
    const int b = bn / Nc;

    compute_a(bn, tid, coord, adj, top_ind, mr, mt, pr, pt,
              lds_idx, lds_a, lds_scale);

    const int m = tid >> 5;
    float ak[Kc];
    size_t rowoff[Kc];
    #pragma unroll
    for (int k = 0; k < Kc; ++k) {
        ak[k] = lds_a[k][m];
        rowoff[k] = (size_t)(b * Nc + lds_idx[k]) * MO + tid * 4;
    }
    float4 acc = make_float4(0.f, 0.f, 0.f, 0.f);
    #pragma unroll
    for (int k = 0; k < Kc; ++k) {
        const float4 p = *(const float4*)&P[rowoff[k]];
        acc.x += ak[k] * p.x; acc.y += ak[k] * p.y;
        acc.z += ak[k] * p.z; acc.w += ak[k] * p.w;
    }
    *(float4*)&out[(size_t)bn * MO + tid * 4] = acc;
}

extern "C" void kernel_launch(void* const* d_in, const int* in_sizes, int n_in,
                              void* d_out, int out_size, void* d_ws, size_t ws_size,
                              hipStream_t stream) {
    const float* v        = (const float*)d_in[0];
    const float* coord    = (const float*)d_in[2];
    const float* adj      = (const float*)d_in[3];
    const int*   top_ind  = (const int*)d_in[4];
    const float* mr       = (const float*)d_in[5];
    const float* mt       = (const float*)d_in[6];
    const float* pr       = (const float*)d_in[7];
    const float* pt       = (const float*)d_in[8];
    const float* W        = (const float*)d_in[9];
    float* out = (float*)d_out;

    const size_t vbBytes = (size_t)BN * Fc * sizeof(unsigned short);   // 26,214,400
    const size_t WbBytes = (size_t)MO * Fc * sizeof(unsigned short);   //  4,194,304
    const size_t awBytes = (size_t)BN * 128 * sizeof(float);           //  3,276,800
    const size_t needBF  = vbBytes + WbBytes + awBytes;                // ~33.7 MB
    const size_t PBytes  = (size_t)BN * MO * sizeof(float);            // 26,214,400

    if (ws_size >= needBF) {
        char* ws = (char*)d_ws;
        unsigned short* vb = (unsigned short*)ws;                 // Wb follows vb
        unsigned short* Wb = vb + (size_t)BN * Fc;
        float* aw          = (float*)(ws + vbBytes + WbBytes);

        const int n8v   = BN * Fc / 8;                 // 1,638,400
        const int nCvt  = (n8v + MO * Fc / 8) / 256;   // 7424 (exact)
        const int nWgt  = BN / 2;                      // 3200
        prep<<<nCvt + nWgt, 256, 0, stream>>>(v, W, vb, n8v, nCvt,
                                              coord, adj, top_ind,
                                              mr, mt, pr, pt, aw);

        gemm_fused<<<512, 512, 0, stream>>>(vb, Wb, aw, top_ind, out);
    } else if (ws_size >= PBytes) {
        float* P = (float*)d_ws;
        gemm_p<<<dim3(BN / TM, MO / TN), 256, 0, stream>>>(v, W, P);
        combine_f32<<<BN, 256, 0, stream>>>(P, coord, adj, top_ind,
                                            mr, mt, pr, pt, out);
    }
}